// Round 2
// baseline (273.953 us; speedup 1.0000x reference)
//
#include <hip/hip_runtime.h>

// BasisEncoder: out[b, :] = one_hot(x[b] % 64, 64) as fp32.
// (x % 256) % 64 == x % 64 since 64 | 256; x >= 0 so & 63 is exact.
//
// R1 changes vs R0:
//  - grid-stride loop: 2048 blocks instead of 65536 -> 32 float4 stores/thread,
//    amortizes workgroup dispatch and gives the wave many stores in flight.
//  - unroll x8: 8 independent x loads issued together (one latency wait),
//    then 8 independent 16B/lane nontemporal stores.
//  - nontemporal stores: 256 MB streaming output, skip L2 write-allocate.
//
// Layout: out is row-major [B, 64] fp32 = [B*16] float4; 16 consecutive
// threads cover one row -> each store instruction is a contiguous 1 KiB/wave.

typedef float f32x4 __attribute__((ext_vector_type(4)));

#define BATCH (1048576)
#define TOTAL_VEC (BATCH * 16)            // 16,777,216 float4 elements

constexpr int TPB = 256;
constexpr int BLOCKS = 2048;              // 8 blocks/CU
constexpr int GRID_THREADS = TPB * BLOCKS;        // 524,288
constexpr int ITERS = TOTAL_VEC / GRID_THREADS;   // 32
constexpr int UNROLL = 8;

__global__ __launch_bounds__(TPB) void basis_encoder_kernel(
    const int* __restrict__ x, f32x4* __restrict__ out) {
  const int tid = blockIdx.x * TPB + threadIdx.x;
  const int base = (tid & 15) << 2;   // first column of this thread's chunk
                                      // (grid stride is a multiple of 16 ->
                                      //  loop-invariant, hoisted)
  #pragma unroll
  for (int outer = 0; outer < ITERS / UNROLL; ++outer) {
    unsigned idx[UNROLL];
    int gid[UNROLL];
    #pragma unroll
    for (int u = 0; u < UNROLL; ++u) {
      gid[u] = tid + (outer * UNROLL + u) * GRID_THREADS;
      idx[u] = (unsigned)x[gid[u] >> 4] & 63u;   // 8 independent loads in flight
    }
    #pragma unroll
    for (int u = 0; u < UNROLL; ++u) {
      f32x4 v;
      v.x = (idx[u] == (unsigned)(base + 0)) ? 1.0f : 0.0f;
      v.y = (idx[u] == (unsigned)(base + 1)) ? 1.0f : 0.0f;
      v.z = (idx[u] == (unsigned)(base + 2)) ? 1.0f : 0.0f;
      v.w = (idx[u] == (unsigned)(base + 3)) ? 1.0f : 0.0f;
      __builtin_nontemporal_store(v, &out[gid[u]]);
    }
  }
}

extern "C" void kernel_launch(void* const* d_in, const int* in_sizes, int n_in,
                              void* d_out, int out_size, void* d_ws, size_t ws_size,
                              hipStream_t stream) {
  const int* x = (const int*)d_in[0];
  f32x4* out = (f32x4*)d_out;
  basis_encoder_kernel<<<BLOCKS, TPB, 0, stream>>>(x, out);
}